// Round 11
// baseline (907.677 us; speedup 1.0000x reference)
//
#include <hip/hip_runtime.h>
#include <math.h>

#define B_ 32
#define T_ 20
#define H_ 256
#define F_ 512
#define NT_ 640

typedef __attribute__((ext_vector_type(8))) _Float16 half8v;
typedef __attribute__((ext_vector_type(4))) float f32x4;

__device__ __forceinline__ float sigf(float x){ return 1.f/(1.f+__expf(-x)); }
__device__ __forceinline__ float lrelu(float x){ return x>0.f ? x : 0.2f*x; }
__device__ __forceinline__ float dot4(float4 a, float4 b){
  return fmaf(a.x,b.x, fmaf(a.y,b.y, fmaf(a.z,b.z, a.w*b.w)));
}
__device__ __forceinline__ unsigned short f16bits(float x){
  _Float16 h = (_Float16)x;                 // RNE
  union { _Float16 h; unsigned short u; } cv; cv.h = h; return cv.u;
}

// Wc = w_ih + w_hh
__global__ void k_wc(const float* __restrict__ wih, const float* __restrict__ whh,
                     float* __restrict__ Wc){
  int i = blockIdx.x*256 + threadIdx.x;
  float4 a = ((const float4*)wih)[i];
  float4 b = ((const float4*)whh)[i];
  ((float4*)Wc)[i] = make_float4(a.x+b.x, a.y+b.y, a.z+b.z, a.w+b.w);
}

// bias1 = b_ih + b_hh ; bias0 = init_inp @ w_ih.T + bias1
__global__ void k_bias(const float* __restrict__ wih, const float* __restrict__ bih,
                       const float* __restrict__ bhh, const float* __restrict__ init_inp,
                       float* __restrict__ bias0, float* __restrict__ bias1){
  __shared__ __align__(16) float xs[H_];
  int tid = threadIdx.x;
  xs[tid] = init_inp[tid];
  __syncthreads();
  int j = blockIdx.x*256 + tid;
  const float4* wr = (const float4*)(wih + (size_t)j*H_);
  const float4* xx = (const float4*)xs;
  float acc = 0.f;
  #pragma unroll 8
  for(int k=0;k<H_/4;k++) acc += dot4(wr[k], xx[k]);
  float b1 = bih[j] + bhh[j];
  bias1[j] = b1;
  bias0[j] = acc + b1;
}

// out[b][j] = z[b] . W[j] + bias[j]
__global__ void k_rowfc(const float* __restrict__ z, const float* __restrict__ W,
                        const float* __restrict__ bias, float* __restrict__ out){
  __shared__ __align__(16) float zs[H_];
  int b = blockIdx.x, j = threadIdx.x;
  zs[j] = z[b*H_ + j];
  __syncthreads();
  const float4* wr = (const float4*)(W + (size_t)j*H_);
  const float4* zz = (const float4*)zs;
  float acc = bias[j];
  #pragma unroll 8
  for(int k=0;k<H_/4;k++) acc += dot4(wr[k], zz[k]);
  out[b*H_+j] = acc;
}

// ---------------------------------------------------------------------------
// Fused LSTM: all 20 steps in one launch. grid(32 batch), block 1024.
// Thread tid owns gate-row tid (g=tid>>8 in {i,f,g,o}, j=tid&255).
// h lives in LDS across steps; c in registers of threads < 256.
__global__ __launch_bounds__(1024) void k_lstm_all(const float* __restrict__ h0,
    const float* __restrict__ c0, const float* __restrict__ whh,
    const float* __restrict__ Wc, const float* __restrict__ bias0,
    const float* __restrict__ bias1, float* __restrict__ outs){
  __shared__ __align__(16) float hs[H_];
  __shared__ float gs[4*H_];
  int b = blockIdx.x, tid = threadIdx.x;
  float c = 0.f;
  if(tid < H_){ c = c0[b*H_ + tid]; hs[tid] = h0[b*H_ + tid]; }
  __syncthreads();
  for(int t=0;t<T_;t++){
    const float* W  = (t==0) ? whh   : Wc;
    const float* bs = (t==0) ? bias0 : bias1;
    const float4* wr = (const float4*)(W + (size_t)tid*H_);
    const float4* hh = (const float4*)hs;
    float acc = bs[tid];
    #pragma unroll 8
    for(int k=0;k<H_/4;k++) acc += dot4(wr[k], hh[k]);
    gs[tid] = acc;
    __syncthreads();
    if(tid < H_){
      float iv = gs[tid], fv = gs[H_+tid], gv = gs[2*H_+tid], ov = gs[3*H_+tid];
      float cn = sigf(fv)*c + sigf(iv)*tanhf(gv);
      c = cn;
      float hn = sigf(ov)*tanhf(cn);
      hs[tid] = hn;
      outs[(t*B_ + b)*H_ + tid] = hn;
    }
    __syncthreads();
  }
}

// feats[n][f] = leaky(outs[t][b] . w[f] + bias[f]),  n = b*T+t
__global__ void k_fcout(const float* __restrict__ outs, const float* __restrict__ w,
                        const float* __restrict__ bias, float* __restrict__ feats){
  __shared__ __align__(16) float hs[H_];
  int n = blockIdx.y; int b = n/T_, t = n - b*T_;
  int tid = threadIdx.x;
  hs[tid] = outs[(t*B_ + b)*H_ + tid];
  __syncthreads();
  int f = blockIdx.x*256 + tid;
  const float4* wr = (const float4*)(w + (size_t)f*H_);
  const float4* hh = (const float4*)hs;
  float acc = bias[f];
  #pragma unroll 8
  for(int k=0;k<H_/4;k++) acc += dot4(wr[k], hh[k]);
  feats[n*F_ + f] = lrelu(acc);
}

// fp32 -> fp16 elementwise (8 per thread)
__global__ void k_wcvt(const float* __restrict__ w, unsigned short* __restrict__ o, int n8){
  int i = blockIdx.x*256 + threadIdx.x;
  if(i >= n8) return;
  int base = i*8;
  float4 v0 = *(const float4*)(w+base);
  float4 v1 = *(const float4*)(w+base+4);
  unsigned short h[8] = {f16bits(v0.x),f16bits(v0.y),f16bits(v0.z),f16bits(v0.w),
                         f16bits(v1.x),f16bits(v1.y),f16bits(v1.z),f16bits(v1.w)};
  *(uint4*)(o+base) = *(uint4*)h;
}

// ---------------------------------------------------------------------------
// MFMA FC: C[m][n] = leaky(A[m][:K] . Wh[n][:K] + bias[n]).  BM=64 BN=128 BK=32.
// 4 waves 2x2. l15->n (coalesced stores), (lh,r)->m.
template<int Kt>
__global__ __launch_bounds__(256) void k_fcmm(const float* __restrict__ A,
    const unsigned short* __restrict__ Wh, const float* __restrict__ bias,
    float* __restrict__ C, int Nt){
  constexpr int NK = Kt/32;
  __shared__ unsigned short at[64*40];
  __shared__ unsigned short bt[128*40];
  const int tid = threadIdx.x;
  const int m0 = blockIdx.x*64, n0 = blockIdx.y*128;
  const int arow = tid>>2, ach = tid&3;
  const float* pa = A + (size_t)(m0+arow)*Kt + ach*8;
  const int brow = tid>>1, bh = tid&1;
  const uint4* pb = (const uint4*)(Wh + (size_t)(n0+brow)*Kt + bh*16);
  float4 a0 = *(const float4*)pa;
  float4 a1 = *(const float4*)(pa+4);
  uint4 b0 = pb[0], b1 = pb[1];

  const int lane = tid&63, wvi = tid>>6;
  const int wm = wvi>>1, wn = wvi&1;
  const int l15 = lane&15, lh = lane>>4;

  f32x4 acc[2][4] = {};
  for(int ks=0; ks<NK; ++ks){
    __syncthreads();
    {
      unsigned short h[8] = {f16bits(a0.x),f16bits(a0.y),f16bits(a0.z),f16bits(a0.w),
                             f16bits(a1.x),f16bits(a1.y),f16bits(a1.z),f16bits(a1.w)};
      *(uint4*)&at[arow*40 + ach*8] = *(uint4*)h;
    }
    *(uint4*)&bt[brow*40 + bh*16    ] = b0;
    *(uint4*)&bt[brow*40 + bh*16 + 8] = b1;
    __syncthreads();
    if(ks+1 < NK){
      a0 = *(const float4*)(pa + (ks+1)*32);
      a1 = *(const float4*)(pa + (ks+1)*32 + 4);
      b0 = pb[(ks+1)*4]; b1 = pb[(ks+1)*4 + 1];
    }
    half8v Af[2], Bf[4];
    #pragma unroll
    for(int a=0;a<2;a++)
      Af[a] = *(const half8v*)&at[(wm*32 + a*16 + l15)*40 + lh*8];
    #pragma unroll
    for(int b=0;b<4;b++)
      Bf[b] = *(const half8v*)&bt[(wn*64 + b*16 + l15)*40 + lh*8];
    #pragma unroll
    for(int a=0;a<2;a++)
      #pragma unroll
      for(int b=0;b<4;b++)
        acc[a][b] = __builtin_amdgcn_mfma_f32_16x16x32_f16(Af[a], Bf[b], acc[a][b], 0, 0, 0);
  }
  #pragma unroll
  for(int b=0;b<4;b++){
    int n = n0 + wn*64 + b*16 + l15;
    float bv = bias[n];
    #pragma unroll
    for(int a=0;a<2;a++){
      #pragma unroll
      for(int r=0;r<4;r++){
        int m = m0 + wm*32 + a*16 + lh*4 + r;
        C[(size_t)m*Nt + n] = lrelu(acc[a][b][r] + bv);
      }
    }
  }
}

// ---------------------------------------------------------------------------
// weight transform: Wz[n=(oc*4+py*2+px)][k=(dy3*3+dx3)*IC+ic] (fp16, k-fastest)
template<int IC, int OC>
__global__ void k_wz(const float* __restrict__ w, unsigned short* __restrict__ Wz){
  constexpr int K9 = 9*IC, N4 = 4*OC;
  int i = blockIdx.x*256 + threadIdx.x;
  if(i >= N4*K9) return;
  int n = i / K9; int k = i - n*K9;
  int oc = n>>2, py = (n>>1)&1, px = n&1;
  int dd = k / IC; int ic = k - dd*IC;
  int dy3 = dd/3, dx3 = dd - 3*dy3;
  int ky = py + 3 - 2*dy3, kx = px + 3 - 2*dx3;
  float v = 0.f;
  if(ky>=0 && ky<4 && kx>=0 && kx<4)
    v = w[(((size_t)ic*OC + oc)*4 + ky)*4 + kx];
  Wz[i] = f16bits(v);
}

// ---------------------------------------------------------------------------
// MFMA implicit-GEMM deconv, fp16 operands, fp32 accum. OPERAND-SWAPPED:
// acc = mfma(Bf, Af, acc) so C cols (l15) = M (coalesced stores) and
// C rows (lh,r) = N (oc wave-uniform per lane-group -> cheap stats).
// Stats: per-(oc,block,wm) float2 partials to scratch (no global atomics).
template<int IC, int OC, int IH, int NL, int RB, int SR, int BM, bool BNIN>
__global__ __launch_bounds__(256) void k_gemmdc(
    const float* __restrict__ in, const unsigned short* __restrict__ Wz,
    float* __restrict__ out, const float* __restrict__ sc, const float* __restrict__ sh,
    float2* __restrict__ scr, int CB)
{
  constexpr int IW = IH, OW = 2*IH;
  constexpr int S  = IH*IW, S4 = 4*S;
  constexpr int K9 = 9*IC;
  constexpr int ICp = IC + 8;
  constexpr int TS = IH/RB;
  constexpr int P  = NL*SR*IW;
  constexpr int NK = K9/32;
  constexpr int BN = 128;
  constexpr int AM = BM/32;
  static_assert(NL*RB*IW == BM, "BM mismatch");

  __shared__ unsigned short linH[P*ICp];
  __shared__ unsigned short bt[BN*32];

  const int tid = threadIdx.x;
  const int bm = blockIdx.x, bn0 = blockIdx.y*BN;
  const int nimg0 = (bm/TS)*NL;
  const int rg = bm % TS;
  const int W0 = (SR==IH) ? 0 : (rg*RB - 1);

  // B prefetch addressing: thread covers (n = tid>>1, half h = tid&1 -> 16 k)
  const int pf_n = tid>>1, pf_h = tid&1;
  const uint4* pf_base = (const uint4*)(Wz + (size_t)(bn0+pf_n)*K9 + pf_h*16);
  uint4 breg0, breg1;

  // ---- stage A slab (fp16 channel-last), fused BN+leaky if BNIN
  {
    constexpr int NIT = P*(IC/8)/256;
    #pragma unroll
    for(int it=0; it<NIT; ++it){
      int i = tid + it*256;
      int p = i % P; int icb = (i/P)*8;
      int x = p % IW; int t1 = p/IW; int j = t1 % SR; int nl = t1/SR;
      int gr = W0 + j;
      bool ok = (gr>=0) && (gr<IH);
      const float* src = in + ((size_t)(nimg0+nl)*IC + icb)*S + gr*IW + x;
      unsigned short hh[8];
      #pragma unroll
      for(int e=0;e<8;e++){
        float v = ok ? src[(size_t)e*S] : 0.f;
        if(BNIN) v = lrelu(fmaf(v, sc[icb+e], sh[icb+e]));
        hh[e] = f16bits(v);
      }
      *(uint4*)&linH[p*ICp + icb] = *(uint4*)hh;
    }
  }
  // prefetch B tile for ks=0
  breg0 = pf_base[0]; breg1 = pf_base[1];

  const int lane = tid & 63, wvi = tid>>6;
  const int wm = wvi>>1, wn = wvi&1;
  const int l15 = lane & 15, lh = lane>>4;

  int mxA[AM], mylA[AM], nlA[AM];
  #pragma unroll
  for(int a=0;a<AM;a++){
    int r = wm*(BM/2) + a*16 + l15;
    mxA[a] = r % IW; int t = r/IW; mylA[a] = t % RB; nlA[a] = t/RB;
  }

  f32x4 acc[AM][4] = {};

  for(int ks=0; ks<NK; ++ks){
    __syncthreads();
    // write prefetched B tile [128 n][32 k]
    *(uint4*)&bt[pf_n*32 + pf_h*16    ] = breg0;
    *(uint4*)&bt[pf_n*32 + pf_h*16 + 8] = breg1;
    __syncthreads();
    // prefetch next tile during compute
    if(ks+1 < NK){
      breg0 = pf_base[(ks+1)*4];
      breg1 = pf_base[(ks+1)*4 + 1];
    }

    int k0 = ks*32;
    int dd = k0 / IC; int icb = k0 - dd*IC;
    int dy3 = dd/3, dx3 = dd - 3*dy3;

    half8v Af[AM], Bf[4];
    #pragma unroll
    for(int a=0;a<AM;a++){
      int gx = mxA[a] - 1 + dx3;
      bool vx = (gx>=0) && (gx<IW);
      int gxc = gx<0 ? 0 : (gx>IW-1 ? IW-1 : gx);
      int jyc; bool vy;
      if(SR==IH){
        int jy = mylA[a] - 1 + dy3;
        vy = (jy>=0) && (jy<IH);
        jyc = jy<0 ? 0 : (jy>SR-1 ? SR-1 : jy);
      } else {
        jyc = mylA[a] + dy3; vy = true;   // halo rows staged (zero-filled OOB)
      }
      int p = (nlA[a]*SR + jyc)*IW + gxc;
      half8v f = *(const half8v*)&linH[p*ICp + icb + lh*8];
      if(!(vx&&vy)){
        #pragma unroll
        for(int e=0;e<8;e++) f[e] = (_Float16)0.f;
      }
      Af[a] = f;
    }
    #pragma unroll
    for(int b=0;b<4;b++)
      Bf[b] = *(const half8v*)&bt[(wn*64 + b*16 + l15)*32 + lh*8];

    // OPERAND SWAP: rows(lh,r)=N, cols(l15)=M
    #pragma unroll
    for(int a=0;a<AM;a++)
      #pragma unroll
      for(int b=0;b<4;b++)
        acc[a][b] = __builtin_amdgcn_mfma_f32_16x16x32_f16(Bf[b], Af[a], acc[a][b], 0, 0, 0);
  }

  // ---- epilogue: coalesced stores (l15 -> mx) + scratch stats
  #pragma unroll
  for(int b=0;b<4;b++){
    float s_ = 0.f, q_ = 0.f;
    int Nbase = bn0 + wn*64 + b*16 + lh*4;
    #pragma unroll
    for(int r=0;r<4;r++){
      int N = Nbase + r;
      int oc = N>>2, py = (N>>1)&1, px = N&1;
      #pragma unroll
      for(int a=0;a<AM;a++){
        float v = acc[a][b][r];
        int myg = (SR==IH) ? mylA[a] : (rg*RB + mylA[a]);
        out[((size_t)(nimg0+nlA[a])*OC + oc)*S4 + (size_t)(2*myg+py)*OW + (2*mxA[a]+px)] = v;
        s_ += v; q_ = fmaf(v,v,q_);
      }
    }
    // reduce over the 16 M-lanes (l15)
    s_ += __shfl_xor(s_,1); q_ += __shfl_xor(q_,1);
    s_ += __shfl_xor(s_,2); q_ += __shfl_xor(q_,2);
    s_ += __shfl_xor(s_,4); q_ += __shfl_xor(q_,4);
    s_ += __shfl_xor(s_,8); q_ += __shfl_xor(q_,8);
    if(l15 == 0){
      int oc = ((bn0 + wn*64 + b*16)>>2) + lh;
      scr[(size_t)oc*CB + bm*2 + wm] = make_float2(s_, q_);
    }
  }
}

// reduce per-block float2 partials -> sum/sq per oc. grid(OC), block 256.
__global__ void k_bnred(const float2* __restrict__ scr, float* __restrict__ sum,
                        float* __restrict__ sq, int CB){
  int oc = blockIdx.x, tid = threadIdx.x;
  float s = 0.f, q = 0.f;
  for(int i = tid; i < CB; i += 256){
    float2 v = scr[(size_t)oc*CB + i];
    s += v.x; q += v.y;
  }
  #pragma unroll
  for(int m=1;m<64;m<<=1){ s += __shfl_xor(s,m); q += __shfl_xor(q,m); }
  __shared__ float ls[4], lq[4];
  int w = tid>>6;
  if((tid&63)==0){ ls[w]=s; lq[w]=q; }
  __syncthreads();
  if(tid==0){
    sum[oc] = ls[0]+ls[1]+ls[2]+ls[3];
    sq[oc]  = lq[0]+lq[1]+lq[2]+lq[3];
  }
}

// in-place BN(training stats) + leaky. x layout (N, OC, SP)
template<int OC, int SP>
__global__ void k_bn(float* __restrict__ x, const float* __restrict__ ssum,
                     const float* __restrict__ ssq, const float* __restrict__ g,
                     const float* __restrict__ be, int n4){
  int i = blockIdx.x*256 + threadIdx.x;
  if(i >= n4) return;
  int c = ((i*4)/SP) % OC;
  const float inv_cnt = 1.f/(640.f*SP);
  float m = ssum[c]*inv_cnt;
  float var = ssq[c]*inv_cnt - m*m;
  float sc = g[c]*rsqrtf(var + 1e-5f);
  float sh = be[c] - m*sc;
  float4 xv = ((float4*)x)[i];
  xv.x = lrelu(fmaf(xv.x, sc, sh));
  xv.y = lrelu(fmaf(xv.y, sc, sh));
  xv.z = lrelu(fmaf(xv.z, sc, sh));
  xv.w = lrelu(fmaf(xv.w, sc, sh));
  ((float4*)x)[i] = xv;
}

// ---------------------------------------------------------------------------
// final ConvTranspose (32->1) + sigmoid (reads post-BN conv2).
__global__ __launch_bounds__(256,3) void k_final(const float* __restrict__ in,
    const float* __restrict__ w, float* __restrict__ dout, const float* __restrict__ fb){
  constexpr int IC = 32, IH = 32, IW = 32, OW = 64, RB = 8, SR = RB+2;
  __shared__ float lin[IC*SR*IW];
  __shared__ __align__(16) float lw[IC*16];

  int rg = blockIdx.x;
  int n = blockIdx.y;
  int tid = threadIdx.x;

  {
    const float4* src = (const float4*)in;
    float4* dst = (float4*)lin;
    constexpr int NV4 = IC*SR*IW/4;
    #pragma unroll
    for(int i=0;i<NV4/256;i++){
      int idx = tid + i*256;
      int ic = idx/(SR*8); int rem = idx - ic*(SR*8);
      int j = rem/8; int c4 = rem - j*8;
      int gr = RB*rg - 1 + j;
      gr = gr < 0 ? 0 : (gr > IH-1 ? IH-1 : gr);
      dst[idx] = src[((size_t)(n*IC+ic)*IH + gr)*8 + c4];
    }
    if(tid < 128) ((float4*)lw)[tid] = ((const float4*)w)[tid];
  }
  float fbv = fb[0];
  __syncthreads();

  int tl = tid / IW, tx = tid % IW;
  int ty = RB*rg + tl;

  int offs[3][3]; float msk[3][3];
  #pragma unroll
  for(int dy=0;dy<3;dy++){
    int iy = ty-1+dy; bool vy = (iy>=0)&&(iy<IH);
    #pragma unroll
    for(int dx=0;dx<3;dx++){
      int ix = tx-1+dx; bool vx = (ix>=0)&&(ix<IW);
      int lcol = ix < 0 ? 0 : (ix > IW-1 ? IW-1 : ix);
      offs[dy][dx] = (tl+dy)*IW + lcol;
      msk[dy][dx]  = (vy&&vx) ? 1.f : 0.f;
    }
  }

  float acc[2][2] = {{0.f,0.f},{0.f,0.f}};
  #pragma unroll 4
  for(int ic=0; ic<IC; ic++){
    const float* p = lin + ic*(SR*IW);
    float v[3][3];
    #pragma unroll
    for(int dy=0;dy<3;dy++)
      #pragma unroll
      for(int dx=0;dx<3;dx++)
        v[dy][dx] = p[offs[dy][dx]] * msk[dy][dx];
    const float4* wr = (const float4*)(lw + ic*16);
    float4 w0=wr[0], w1=wr[1], w2=wr[2], w3=wr[3];
    float wv[16] = {w0.x,w0.y,w0.z,w0.w, w1.x,w1.y,w1.z,w1.w,
                    w2.x,w2.y,w2.z,w2.w, w3.x,w3.y,w3.z,w3.w};
    #pragma unroll
    for(int r=0;r<2;r++)
      #pragma unroll
      for(int s2=0;s2<2;s2++)
        #pragma unroll
        for(int a=0;a<2;a++)
          #pragma unroll
          for(int b2=0;b2<2;b2++)
            acc[r][s2] = fmaf(v[a+r][b2+s2], wv[(3-2*a-r)*4 + (3-2*b2-s2)], acc[r][s2]);
  }

  float* ob = dout + (size_t)n*OW*OW;
  #pragma unroll
  for(int r=0;r<2;r++)
    #pragma unroll
    for(int s2=0;s2<2;s2++){
      float vv = acc[r][s2] + fbv;
      ob[(2*ty+r)*OW + (2*tx+s2)] = 1.f/(1.f+__expf(-vv));
    }
}

extern "C" void kernel_launch(void* const* d_in, const int* in_sizes, int n_in,
                              void* d_out, int out_size, void* d_ws, size_t ws_size,
                              hipStream_t stream){
  const float* z       = (const float*)d_in[0];
  const float* fhw     = (const float*)d_in[1];
  const float* fhb     = (const float*)d_in[2];
  const float* fcw     = (const float*)d_in[3];
  const float* fcb     = (const float*)d_in[4];
  const float* wih     = (const float*)d_in[5];
  const float* bih     = (const float*)d_in[6];
  const float* whh     = (const float*)d_in[7];
  const float* bhh     = (const float*)d_in[8];
  const float* init_inp= (const float*)d_in[9];
  const float* fow     = (const float*)d_in[10];
  const float* fob     = (const float*)d_in[11];
  const float* cfw     = (const float*)d_in[12];
  const float* cfb     = (const float*)d_in[13];
  const float* dw0     = (const float*)d_in[14];
  const float* g0      = (const float*)d_in[15];
  const float* be0     = (const float*)d_in[16];
  const float* dw1     = (const float*)d_in[17];
  const float* g1      = (const float*)d_in[18];
  const float* be1     = (const float*)d_in[19];
  const float* dw2     = (const float*)d_in[20];
  const float* g2      = (const float*)d_in[21];
  const float* be2     = (const float*)d_in[22];
  const float* fw      = (const float*)d_in[23];
  const float* fb      = (const float*)d_in[24];

  float* ws    = (float*)d_ws;
  float* conv2 = ws;                 // 640*32*1024 = 20971520 floats
  float* conv1 = ws + 20971520;      // 640*64*256  = 10485760
  float* conv0 = ws + 31457280;      // 640*128*64  =  5242880
  float* fc1   = ws + 36700160;      // 640*4096    =  2621440
  float* feats = ws + 39321600;      // 640*512     =   327680
  float* outs  = ws + 39649280;      // 20*32*256   =   163840
  float* Wc    = ws + 39813120;      // 1024*256    =   262144
  float* bias0 = ws + 40075264;      // 1024
  float* bias1 = ws + 40076288;      // 1024
  float* h0    = ws + 40077312;      // 8192
  float* cbuf  = ws + 40085504;      // 8192
  float* stats = ws + 40093696;      // 448
  float* sum0 = stats,     *sq0 = stats+128;
  float* sum1 = stats+256, *sq1 = stats+320;
  float* sum2 = stats+384, *sq2 = stats+416;

  // transformed weights + stats scratch live in regions dead at use time:
  //  Wz0 @ conv2+0 (589824 fl), Wz1 @ conv2+600000 (147456 fl),
  //  Whf (cnnfc fp16 weights) @ conv2+1000000 (1048576 fl) — all consumed
  //  before the L2 gemm writes conv2.
  //  scr0/scr1 in outs (dead after k_fcout); scr2 in feats+40960 (dead after k_fcmm)
  unsigned short* Wz0 = (unsigned short*)conv2;
  unsigned short* Wz1 = (unsigned short*)(conv2 + 600000);
  unsigned short* Whf = (unsigned short*)(conv2 + 1000000);     // 4096*512 f16
  unsigned short* Wz2 = (unsigned short*)feats;                 // 128*576 f16
  float2* scr0 = (float2*)outs;                 // 128 oc * 320 = 40960 float2
  float2* scr1 = (float2*)(outs + 81920);       // 64 oc * 640  = 40960 float2
  float2* scr2 = (float2*)(feats + 40960);      // 32 oc * 2560 = 81920 float2

  hipLaunchKernelGGL(k_wc,    dim3(256), dim3(256), 0, stream, wih, whh, Wc);
  hipLaunchKernelGGL(k_bias,  dim3(4),   dim3(256), 0, stream, wih, bih, bhh, init_inp, bias0, bias1);
  hipLaunchKernelGGL(k_rowfc, dim3(32),  dim3(256), 0, stream, z, fhw, fhb, h0);
  hipLaunchKernelGGL(k_rowfc, dim3(32),  dim3(256), 0, stream, z, fcw, fcb, cbuf);
  hipLaunchKernelGGL(k_wcvt,  dim3(1024), dim3(256), 0, stream, cfw, Whf, 262144);

  // fused LSTM: 20 steps, one launch
  hipLaunchKernelGGL(k_lstm_all, dim3(32), dim3(1024), 0, stream,
                     h0, cbuf, whh, Wc, bias0, bias1, outs);

  hipLaunchKernelGGL(k_fcout, dim3(2,NT_), dim3(256), 0, stream, outs, fow, fob, feats);
  // cnnfc as MFMA GEMM: M=640 N=4096 K=512, grid(10,32)
  hipLaunchKernelGGL((k_fcmm<512>), dim3(10,32), dim3(256), 0, stream, feats, Whf, cfb, fc1, 4096);

  hipLaunchKernelGGL((k_wz<256,128>), dim3(4608), dim3(256), 0, stream, dw0, Wz0);
  hipLaunchKernelGGL((k_wz<128,64>),  dim3(1152), dim3(256), 0, stream, dw1, Wz1);
  hipLaunchKernelGGL((k_wz<64,32>),   dim3(288),  dim3(256), 0, stream, dw2, Wz2);

  // L0 (MFMA): IC=256 OC=128 IH=4, NL=4 RB=4 SR=4 BM=64, grid(160,4), CB=320
  hipLaunchKernelGGL((k_gemmdc<256,128,4,4,4,4,64,false>), dim3(160,4), dim3(256), 0, stream,
                     fc1, Wz0, conv0, (const float*)nullptr, (const float*)nullptr, scr0, 320);
  hipLaunchKernelGGL(k_bnred, dim3(128), dim3(256), 0, stream, scr0, sum0, sq0, 320);
  hipLaunchKernelGGL((k_bn<128,64>),   dim3(5120),  dim3(256), 0, stream, conv0, sum0, sq0, g0, be0, 1310720);

  // L1 (MFMA): IC=128 OC=64 IH=8, NL=2 RB=8 SR=8 BM=128, grid(320,2), CB=640
  hipLaunchKernelGGL((k_gemmdc<128,64,8,2,8,8,128,false>), dim3(320,2), dim3(256), 0, stream,
                     conv0, Wz1, conv1, (const float*)nullptr, (const float*)nullptr, scr1, 640);
  hipLaunchKernelGGL(k_bnred, dim3(64), dim3(256), 0, stream, scr1, sum1, sq1, 640);
  hipLaunchKernelGGL((k_bn<64,256>),   dim3(10240), dim3(256), 0, stream, conv1, sum1, sq1, g1, be1, 2621440);

  // L2 (MFMA): IC=64 OC=32 IH=16, NL=1 RB=8 SR=10 BM=128, grid(1280,1), CB=2560
  hipLaunchKernelGGL((k_gemmdc<64,32,16,1,8,10,128,false>), dim3(1280,1), dim3(256), 0, stream,
                     conv1, Wz2, conv2, (const float*)nullptr, (const float*)nullptr, scr2, 2560);
  hipLaunchKernelGGL(k_bnred, dim3(32), dim3(256), 0, stream, scr2, sum2, sq2, 2560);
  hipLaunchKernelGGL((k_bn<32,1024>),  dim3(20480), dim3(256), 0, stream, conv2, sum2, sq2, g2, be2, 5242880);

  // final
  hipLaunchKernelGGL(k_final, dim3(4,640), dim3(256), 0, stream, conv2, fw, (float*)d_out, fb);
}

// Round 12
// 494.271 us; speedup vs baseline: 1.8364x; 1.8364x over previous
//
#include <hip/hip_runtime.h>
#include <math.h>

#define B_ 32
#define T_ 20
#define H_ 256
#define F_ 512
#define NT_ 640

typedef __attribute__((ext_vector_type(8))) _Float16 half8v;
typedef __attribute__((ext_vector_type(4))) float f32x4;

__device__ __forceinline__ float sigf(float x){ return 1.f/(1.f+__expf(-x)); }
__device__ __forceinline__ float lrelu(float x){ return x>0.f ? x : 0.2f*x; }
__device__ __forceinline__ float dot4(float4 a, float4 b){
  return fmaf(a.x,b.x, fmaf(a.y,b.y, fmaf(a.z,b.z, a.w*b.w)));
}
__device__ __forceinline__ unsigned short f16bits(float x){
  _Float16 h = (_Float16)x;                 // RNE
  union { _Float16 h; unsigned short u; } cv; cv.h = h; return cv.u;
}

// Wc = w_ih + w_hh
__global__ void k_wc(const float* __restrict__ wih, const float* __restrict__ whh,
                     float* __restrict__ Wc){
  int i = blockIdx.x*256 + threadIdx.x;
  float4 a = ((const float4*)wih)[i];
  float4 b = ((const float4*)whh)[i];
  ((float4*)Wc)[i] = make_float4(a.x+b.x, a.y+b.y, a.z+b.z, a.w+b.w);
}

// bias1 = b_ih + b_hh ; bias0 = init_inp @ w_ih.T + bias1
__global__ void k_bias(const float* __restrict__ wih, const float* __restrict__ bih,
                       const float* __restrict__ bhh, const float* __restrict__ init_inp,
                       float* __restrict__ bias0, float* __restrict__ bias1){
  __shared__ __align__(16) float xs[H_];
  int tid = threadIdx.x;
  xs[tid] = init_inp[tid];
  __syncthreads();
  int j = blockIdx.x*256 + tid;
  const float4* wr = (const float4*)(wih + (size_t)j*H_);
  const float4* xx = (const float4*)xs;
  float acc = 0.f;
  #pragma unroll 8
  for(int k=0;k<H_/4;k++) acc += dot4(wr[k], xx[k]);
  float b1 = bih[j] + bhh[j];
  bias1[j] = b1;
  bias0[j] = acc + b1;
}

// out[b][j] = z[b] . W[j] + bias[j]
__global__ void k_rowfc(const float* __restrict__ z, const float* __restrict__ W,
                        const float* __restrict__ bias, float* __restrict__ out){
  __shared__ __align__(16) float zs[H_];
  int b = blockIdx.x, j = threadIdx.x;
  zs[j] = z[b*H_ + j];
  __syncthreads();
  const float4* wr = (const float4*)(W + (size_t)j*H_);
  const float4* zz = (const float4*)zs;
  float acc = bias[j];
  #pragma unroll 8
  for(int k=0;k<H_/4;k++) acc += dot4(wr[k], zz[k]);
  out[b*H_+j] = acc;
}

// one LSTM step. n-order output: hout[b*ho_stride + j]. grid (4,32), block 256.
__global__ void k_lstm(const float* __restrict__ hprev, int hp_stride,
                       float* __restrict__ c,
                       const float* __restrict__ W, const float* __restrict__ bias,
                       float* __restrict__ hout, int ho_stride){
  __shared__ __align__(16) float hs[H_];
  __shared__ float gs[4][64];
  int b = blockIdx.y, jg = blockIdx.x, tid = threadIdx.x;
  hs[tid] = hprev[(size_t)b*hp_stride + tid];
  __syncthreads();
  int g = tid>>6, jj = tid&63;
  int row = g*H_ + jg*64 + jj;
  const float4* wr = (const float4*)(W + (size_t)row*H_);
  const float4* hh = (const float4*)hs;
  float acc = bias[row];
  #pragma unroll 8
  for(int k=0;k<H_/4;k++) acc += dot4(wr[k], hh[k]);
  gs[g][jj] = acc;
  __syncthreads();
  if(tid < 64){
    int j = jg*64 + tid;
    float iv = gs[0][tid], fv = gs[1][tid], gv = gs[2][tid], ov = gs[3][tid];
    int ci = b*H_ + j;
    float cn = sigf(fv)*c[ci] + sigf(iv)*tanhf(gv);
    c[ci] = cn;
    hout[(size_t)b*ho_stride + j] = sigf(ov)*tanhf(cn);
  }
}

// fp32 -> fp16 elementwise (8 per thread)
__global__ void k_wcvt(const float* __restrict__ w, unsigned short* __restrict__ o, int n8){
  int i = blockIdx.x*256 + threadIdx.x;
  if(i >= n8) return;
  int base = i*8;
  float4 v0 = *(const float4*)(w+base);
  float4 v1 = *(const float4*)(w+base+4);
  unsigned short h[8] = {f16bits(v0.x),f16bits(v0.y),f16bits(v0.z),f16bits(v0.w),
                         f16bits(v1.x),f16bits(v1.y),f16bits(v1.z),f16bits(v1.w)};
  *(uint4*)(o+base) = *(uint4*)h;
}

// ---------------------------------------------------------------------------
// MFMA FC: C[m][n] = leaky(A[m][:K] . Wh[n][:K] + bias[n]).  BM=64 BN=128 BK=32.
// 4 waves 2x2. l15->n (coalesced stores), (lh,r)->m.
template<int Kt>
__global__ __launch_bounds__(256) void k_fcmm(const float* __restrict__ A,
    const unsigned short* __restrict__ Wh, const float* __restrict__ bias,
    float* __restrict__ C, int Nt){
  constexpr int NK = Kt/32;
  __shared__ unsigned short at[64*40];
  __shared__ unsigned short bt[128*40];
  const int tid = threadIdx.x;
  const int m0 = blockIdx.x*64, n0 = blockIdx.y*128;
  const int arow = tid>>2, ach = tid&3;
  const float* pa = A + (size_t)(m0+arow)*Kt + ach*8;
  const int brow = tid>>1, bh = tid&1;
  const uint4* pb = (const uint4*)(Wh + (size_t)(n0+brow)*Kt + bh*16);
  float4 a0 = *(const float4*)pa;
  float4 a1 = *(const float4*)(pa+4);
  uint4 b0 = pb[0], b1 = pb[1];

  const int lane = tid&63, wvi = tid>>6;
  const int wm = wvi>>1, wn = wvi&1;
  const int l15 = lane&15, lh = lane>>4;

  f32x4 acc[2][4] = {};
  for(int ks=0; ks<NK; ++ks){
    __syncthreads();
    {
      unsigned short h[8] = {f16bits(a0.x),f16bits(a0.y),f16bits(a0.z),f16bits(a0.w),
                             f16bits(a1.x),f16bits(a1.y),f16bits(a1.z),f16bits(a1.w)};
      *(uint4*)&at[arow*40 + ach*8] = *(uint4*)h;
    }
    *(uint4*)&bt[brow*40 + bh*16    ] = b0;
    *(uint4*)&bt[brow*40 + bh*16 + 8] = b1;
    __syncthreads();
    if(ks+1 < NK){
      a0 = *(const float4*)(pa + (ks+1)*32);
      a1 = *(const float4*)(pa + (ks+1)*32 + 4);
      b0 = pb[(ks+1)*4]; b1 = pb[(ks+1)*4 + 1];
    }
    half8v Af[2], Bf[4];
    #pragma unroll
    for(int a=0;a<2;a++)
      Af[a] = *(const half8v*)&at[(wm*32 + a*16 + l15)*40 + lh*8];
    #pragma unroll
    for(int b=0;b<4;b++)
      Bf[b] = *(const half8v*)&bt[(wn*64 + b*16 + l15)*40 + lh*8];
    #pragma unroll
    for(int a=0;a<2;a++)
      #pragma unroll
      for(int b=0;b<4;b++)
        acc[a][b] = __builtin_amdgcn_mfma_f32_16x16x32_f16(Af[a], Bf[b], acc[a][b], 0, 0, 0);
  }
  #pragma unroll
  for(int b=0;b<4;b++){
    int n = n0 + wn*64 + b*16 + l15;
    float bv = bias[n];
    #pragma unroll
    for(int a=0;a<2;a++){
      #pragma unroll
      for(int r=0;r<4;r++){
        int m = m0 + wm*32 + a*16 + lh*4 + r;
        C[(size_t)m*Nt + n] = lrelu(acc[a][b][r] + bv);
      }
    }
  }
}

// ---------------------------------------------------------------------------
// weight transform: Wz[n=(oc*4+py*2+px)][k=(dy3*3+dx3)*IC+ic] (fp16, k-fastest)
template<int IC, int OC>
__global__ void k_wz(const float* __restrict__ w, unsigned short* __restrict__ Wz){
  constexpr int K9 = 9*IC, N4 = 4*OC;
  int i = blockIdx.x*256 + threadIdx.x;
  if(i >= N4*K9) return;
  int n = i / K9; int k = i - n*K9;
  int oc = n>>2, py = (n>>1)&1, px = n&1;
  int dd = k / IC; int ic = k - dd*IC;
  int dy3 = dd/3, dx3 = dd - 3*dy3;
  int ky = py + 3 - 2*dy3, kx = px + 3 - 2*dx3;
  float v = 0.f;
  if(ky>=0 && ky<4 && kx>=0 && kx<4)
    v = w[(((size_t)ic*OC + oc)*4 + ky)*4 + kx];
  Wz[i] = f16bits(v);
}

// ---------------------------------------------------------------------------
// MFMA implicit-GEMM deconv, fp16 operands, fp32 accum. OPERAND-SWAPPED:
// acc = mfma(Bf, Af, acc) so C cols (l15) = M (coalesced stores) and
// C rows (lh,r) = N (oc wave-uniform per lane-group -> cheap stats).
// Stats: per-(oc,block,wm) float2 partials to scratch (no global atomics).
template<int IC, int OC, int IH, int NL, int RB, int SR, int BM, bool BNIN>
__global__ __launch_bounds__(256) void k_gemmdc(
    const float* __restrict__ in, const unsigned short* __restrict__ Wz,
    float* __restrict__ out, const float* __restrict__ sc, const float* __restrict__ sh,
    float2* __restrict__ scr, int CB)
{
  constexpr int IW = IH, OW = 2*IH;
  constexpr int S  = IH*IW, S4 = 4*S;
  constexpr int K9 = 9*IC;
  constexpr int ICp = IC + 8;
  constexpr int TS = IH/RB;
  constexpr int P  = NL*SR*IW;
  constexpr int NK = K9/32;
  constexpr int BN = 128;
  constexpr int AM = BM/32;
  static_assert(NL*RB*IW == BM, "BM mismatch");

  __shared__ unsigned short linH[P*ICp];
  __shared__ unsigned short bt[BN*32];

  const int tid = threadIdx.x;
  const int bm = blockIdx.x, bn0 = blockIdx.y*BN;
  const int nimg0 = (bm/TS)*NL;
  const int rg = bm % TS;
  const int W0 = (SR==IH) ? 0 : (rg*RB - 1);

  // B prefetch addressing: thread covers (n = tid>>1, half h = tid&1 -> 16 k)
  const int pf_n = tid>>1, pf_h = tid&1;
  const uint4* pf_base = (const uint4*)(Wz + (size_t)(bn0+pf_n)*K9 + pf_h*16);
  uint4 breg0, breg1;

  // ---- stage A slab (fp16 channel-last), fused BN+leaky if BNIN
  {
    constexpr int NIT = P*(IC/8)/256;
    #pragma unroll
    for(int it=0; it<NIT; ++it){
      int i = tid + it*256;
      int p = i % P; int icb = (i/P)*8;
      int x = p % IW; int t1 = p/IW; int j = t1 % SR; int nl = t1/SR;
      int gr = W0 + j;
      bool ok = (gr>=0) && (gr<IH);
      const float* src = in + ((size_t)(nimg0+nl)*IC + icb)*S + gr*IW + x;
      unsigned short hh[8];
      #pragma unroll
      for(int e=0;e<8;e++){
        float v = ok ? src[(size_t)e*S] : 0.f;
        if(BNIN) v = lrelu(fmaf(v, sc[icb+e], sh[icb+e]));
        hh[e] = f16bits(v);
      }
      *(uint4*)&linH[p*ICp + icb] = *(uint4*)hh;
    }
  }
  // prefetch B tile for ks=0
  breg0 = pf_base[0]; breg1 = pf_base[1];

  const int lane = tid & 63, wvi = tid>>6;
  const int wm = wvi>>1, wn = wvi&1;
  const int l15 = lane & 15, lh = lane>>4;

  int mxA[AM], mylA[AM], nlA[AM];
  #pragma unroll
  for(int a=0;a<AM;a++){
    int r = wm*(BM/2) + a*16 + l15;
    mxA[a] = r % IW; int t = r/IW; mylA[a] = t % RB; nlA[a] = t/RB;
  }

  f32x4 acc[AM][4] = {};

  for(int ks=0; ks<NK; ++ks){
    __syncthreads();
    // write prefetched B tile [128 n][32 k]
    *(uint4*)&bt[pf_n*32 + pf_h*16    ] = breg0;
    *(uint4*)&bt[pf_n*32 + pf_h*16 + 8] = breg1;
    __syncthreads();
    // prefetch next tile during compute
    if(ks+1 < NK){
      breg0 = pf_base[(ks+1)*4];
      breg1 = pf_base[(ks+1)*4 + 1];
    }

    int k0 = ks*32;
    int dd = k0 / IC; int icb = k0 - dd*IC;
    int dy3 = dd/3, dx3 = dd - 3*dy3;

    half8v Af[AM], Bf[4];
    #pragma unroll
    for(int a=0;a<AM;a++){
      int gx = mxA[a] - 1 + dx3;
      bool vx = (gx>=0) && (gx<IW);
      int gxc = gx<0 ? 0 : (gx>IW-1 ? IW-1 : gx);
      int jyc; bool vy;
      if(SR==IH){
        int jy = mylA[a] - 1 + dy3;
        vy = (jy>=0) && (jy<IH);
        jyc = jy<0 ? 0 : (jy>SR-1 ? SR-1 : jy);
      } else {
        jyc = mylA[a] + dy3; vy = true;   // halo rows staged (zero-filled OOB)
      }
      int p = (nlA[a]*SR + jyc)*IW + gxc;
      half8v f = *(const half8v*)&linH[p*ICp + icb + lh*8];
      if(!(vx&&vy)){
        #pragma unroll
        for(int e=0;e<8;e++) f[e] = (_Float16)0.f;
      }
      Af[a] = f;
    }
    #pragma unroll
    for(int b=0;b<4;b++)
      Bf[b] = *(const half8v*)&bt[(wn*64 + b*16 + l15)*32 + lh*8];

    // OPERAND SWAP: rows(lh,r)=N, cols(l15)=M
    #pragma unroll
    for(int a=0;a<AM;a++)
      #pragma unroll
      for(int b=0;b<4;b++)
        acc[a][b] = __builtin_amdgcn_mfma_f32_16x16x32_f16(Bf[b], Af[a], acc[a][b], 0, 0, 0);
  }

  // ---- epilogue: coalesced stores (l15 -> mx) + scratch stats
  #pragma unroll
  for(int b=0;b<4;b++){
    float s_ = 0.f, q_ = 0.f;
    int Nbase = bn0 + wn*64 + b*16 + lh*4;
    #pragma unroll
    for(int r=0;r<4;r++){
      int N = Nbase + r;
      int oc = N>>2, py = (N>>1)&1, px = N&1;
      #pragma unroll
      for(int a=0;a<AM;a++){
        float v = acc[a][b][r];
        int myg = (SR==IH) ? mylA[a] : (rg*RB + mylA[a]);
        out[((size_t)(nimg0+nlA[a])*OC + oc)*S4 + (size_t)(2*myg+py)*OW + (2*mxA[a]+px)] = v;
        s_ += v; q_ = fmaf(v,v,q_);
      }
    }
    // reduce over the 16 M-lanes (l15)
    s_ += __shfl_xor(s_,1); q_ += __shfl_xor(q_,1);
    s_ += __shfl_xor(s_,2); q_ += __shfl_xor(q_,2);
    s_ += __shfl_xor(s_,4); q_ += __shfl_xor(q_,4);
    s_ += __shfl_xor(s_,8); q_ += __shfl_xor(q_,8);
    if(l15 == 0){
      int oc = ((bn0 + wn*64 + b*16)>>2) + lh;
      scr[(size_t)oc*CB + bm*2 + wm] = make_float2(s_, q_);
    }
  }
}

// reduce per-block float2 partials -> sum/sq per oc. grid(OC), block 256.
__global__ void k_bnred(const float2* __restrict__ scr, float* __restrict__ sum,
                        float* __restrict__ sq, int CB){
  int oc = blockIdx.x, tid = threadIdx.x;
  float s = 0.f, q = 0.f;
  for(int i = tid; i < CB; i += 256){
    float2 v = scr[(size_t)oc*CB + i];
    s += v.x; q += v.y;
  }
  #pragma unroll
  for(int m=1;m<64;m<<=1){ s += __shfl_xor(s,m); q += __shfl_xor(q,m); }
  __shared__ float ls[4], lq[4];
  int w = tid>>6;
  if((tid&63)==0){ ls[w]=s; lq[w]=q; }
  __syncthreads();
  if(tid==0){
    sum[oc] = ls[0]+ls[1]+ls[2]+ls[3];
    sq[oc]  = lq[0]+lq[1]+lq[2]+lq[3];
  }
}

// in-place BN(training stats) + leaky. x layout (N, OC, SP)
template<int OC, int SP>
__global__ void k_bn(float* __restrict__ x, const float* __restrict__ ssum,
                     const float* __restrict__ ssq, const float* __restrict__ g,
                     const float* __restrict__ be, int n4){
  int i = blockIdx.x*256 + threadIdx.x;
  if(i >= n4) return;
  int c = ((i*4)/SP) % OC;
  const float inv_cnt = 1.f/(640.f*SP);
  float m = ssum[c]*inv_cnt;
  float var = ssq[c]*inv_cnt - m*m;
  float sc = g[c]*rsqrtf(var + 1e-5f);
  float sh = be[c] - m*sc;
  float4 xv = ((float4*)x)[i];
  xv.x = lrelu(fmaf(xv.x, sc, sh));
  xv.y = lrelu(fmaf(xv.y, sc, sh));
  xv.z = lrelu(fmaf(xv.z, sc, sh));
  xv.w = lrelu(fmaf(xv.w, sc, sh));
  ((float4*)x)[i] = xv;
}

// ---------------------------------------------------------------------------
// final ConvTranspose (32->1) + sigmoid (reads post-BN conv2).
__global__ __launch_bounds__(256,3) void k_final(const float* __restrict__ in,
    const float* __restrict__ w, float* __restrict__ dout, const float* __restrict__ fb){
  constexpr int IC = 32, IH = 32, IW = 32, OW = 64, RB = 8, SR = RB+2;
  __shared__ float lin[IC*SR*IW];
  __shared__ __align__(16) float lw[IC*16];

  int rg = blockIdx.x;
  int n = blockIdx.y;
  int tid = threadIdx.x;

  {
    const float4* src = (const float4*)in;
    float4* dst = (float4*)lin;
    constexpr int NV4 = IC*SR*IW/4;
    #pragma unroll
    for(int i=0;i<NV4/256;i++){
      int idx = tid + i*256;
      int ic = idx/(SR*8); int rem = idx - ic*(SR*8);
      int j = rem/8; int c4 = rem - j*8;
      int gr = RB*rg - 1 + j;
      gr = gr < 0 ? 0 : (gr > IH-1 ? IH-1 : gr);
      dst[idx] = src[((size_t)(n*IC+ic)*IH + gr)*8 + c4];
    }
    if(tid < 128) ((float4*)lw)[tid] = ((const float4*)w)[tid];
  }
  float fbv = fb[0];
  __syncthreads();

  int tl = tid / IW, tx = tid % IW;
  int ty = RB*rg + tl;

  int offs[3][3]; float msk[3][3];
  #pragma unroll
  for(int dy=0;dy<3;dy++){
    int iy = ty-1+dy; bool vy = (iy>=0)&&(iy<IH);
    #pragma unroll
    for(int dx=0;dx<3;dx++){
      int ix = tx-1+dx; bool vx = (ix>=0)&&(ix<IW);
      int lcol = ix < 0 ? 0 : (ix > IW-1 ? IW-1 : ix);
      offs[dy][dx] = (tl+dy)*IW + lcol;
      msk[dy][dx]  = (vy&&vx) ? 1.f : 0.f;
    }
  }

  float acc[2][2] = {{0.f,0.f},{0.f,0.f}};
  #pragma unroll 4
  for(int ic=0; ic<IC; ic++){
    const float* p = lin + ic*(SR*IW);
    float v[3][3];
    #pragma unroll
    for(int dy=0;dy<3;dy++)
      #pragma unroll
      for(int dx=0;dx<3;dx++)
        v[dy][dx] = p[offs[dy][dx]] * msk[dy][dx];
    const float4* wr = (const float4*)(lw + ic*16);
    float4 w0=wr[0], w1=wr[1], w2=wr[2], w3=wr[3];
    float wv[16] = {w0.x,w0.y,w0.z,w0.w, w1.x,w1.y,w1.z,w1.w,
                    w2.x,w2.y,w2.z,w2.w, w3.x,w3.y,w3.z,w3.w};
    #pragma unroll
    for(int r=0;r<2;r++)
      #pragma unroll
      for(int s2=0;s2<2;s2++)
        #pragma unroll
        for(int a=0;a<2;a++)
          #pragma unroll
          for(int b2=0;b2<2;b2++)
            acc[r][s2] = fmaf(v[a+r][b2+s2], wv[(3-2*a-r)*4 + (3-2*b2-s2)], acc[r][s2]);
  }

  float* ob = dout + (size_t)n*OW*OW;
  #pragma unroll
  for(int r=0;r<2;r++)
    #pragma unroll
    for(int s2=0;s2<2;s2++){
      float vv = acc[r][s2] + fbv;
      ob[(2*ty+r)*OW + (2*tx+s2)] = 1.f/(1.f+__expf(-vv));
    }
}

extern "C" void kernel_launch(void* const* d_in, const int* in_sizes, int n_in,
                              void* d_out, int out_size, void* d_ws, size_t ws_size,
                              hipStream_t stream){
  const float* z       = (const float*)d_in[0];
  const float* fhw     = (const float*)d_in[1];
  const float* fhb     = (const float*)d_in[2];
  const float* fcw     = (const float*)d_in[3];
  const float* fcb     = (const float*)d_in[4];
  const float* wih     = (const float*)d_in[5];
  const float* bih     = (const float*)d_in[6];
  const float* whh     = (const float*)d_in[7];
  const float* bhh     = (const float*)d_in[8];
  const float* init_inp= (const float*)d_in[9];
  const float* fow     = (const float*)d_in[10];
  const float* fob     = (const float*)d_in[11];
  const float* cfw     = (const float*)d_in[12];
  const float* cfb     = (const float*)d_in[13];
  const float* dw0     = (const float*)d_in[14];
  const float* g0      = (const float*)d_in[15];
  const float* be0     = (const float*)d_in[16];
  const float* dw1     = (const float*)d_in[17];
  const float* g1      = (const float*)d_in[18];
  const float* be1     = (const float*)d_in[19];
  const float* dw2     = (const float*)d_in[20];
  const float* g2      = (const float*)d_in[21];
  const float* be2     = (const float*)d_in[22];
  const float* fw      = (const float*)d_in[23];
  const float* fb      = (const float*)d_in[24];

  float* ws    = (float*)d_ws;
  float* conv2 = ws;                 // 640*32*1024 = 20971520 floats
  float* conv1 = ws + 20971520;      // 640*64*256  = 10485760
  float* conv0 = ws + 31457280;      // 640*128*64  =  5242880
  float* fc1   = ws + 36700160;      // 640*4096    =  2621440
  float* feats = ws + 39321600;      // 640*512     =   327680
  float* outs  = ws + 39649280;      // 640*256     =   163840 (n-order h)
  float* Wc    = ws + 39813120;      // 1024*256    =   262144
  float* bias0 = ws + 40075264;      // 1024
  float* bias1 = ws + 40076288;      // 1024
  float* h0    = ws + 40077312;      // 8192
  float* cbuf  = ws + 40085504;      // 8192
  float* stats = ws + 40093696;      // 448
  float* sum0 = stats,     *sq0 = stats+128;
  float* sum1 = stats+256, *sq1 = stats+320;
  float* sum2 = stats+384, *sq2 = stats+416;

  // transformed weights + stats scratch live in regions dead at use time:
  //  Wz0 @ conv2+0, Wz1 @ conv2+600000, Whf (cnnfc f16) @ conv2+1000000,
  //  Fof (fcout f16) @ conv2+2100000 — all consumed before L2 writes conv2.
  //  scr0/scr1 in outs (dead after fcout-fcmm); scr2 in feats+40960 (dead after cnnfc-fcmm)
  unsigned short* Wz0 = (unsigned short*)conv2;
  unsigned short* Wz1 = (unsigned short*)(conv2 + 600000);
  unsigned short* Whf = (unsigned short*)(conv2 + 1000000);     // 4096*512 f16
  unsigned short* Fof = (unsigned short*)(conv2 + 2100000);     // 512*256 f16
  unsigned short* Wz2 = (unsigned short*)feats;                 // 128*576 f16
  float2* scr0 = (float2*)outs;                 // 128 oc * 320 = 40960 float2
  float2* scr1 = (float2*)(outs + 81920);       // 64 oc * 640  = 40960 float2
  float2* scr2 = (float2*)(feats + 40960);      // 32 oc * 2560 = 81920 float2

  hipLaunchKernelGGL(k_wc,    dim3(256), dim3(256), 0, stream, wih, whh, Wc);
  hipLaunchKernelGGL(k_bias,  dim3(4),   dim3(256), 0, stream, wih, bih, bhh, init_inp, bias0, bias1);
  hipLaunchKernelGGL(k_rowfc, dim3(32),  dim3(256), 0, stream, z, fhw, fhb, h0);
  hipLaunchKernelGGL(k_rowfc, dim3(32),  dim3(256), 0, stream, z, fcw, fcb, cbuf);
  hipLaunchKernelGGL(k_wcvt,  dim3(1024), dim3(256), 0, stream, cfw, Whf, 262144);
  hipLaunchKernelGGL(k_wcvt,  dim3(64),   dim3(256), 0, stream, fow, Fof, 16384);

  // LSTM: 20 per-step launches (proven fast), n-order output
  for(int t=0;t<T_;t++){
    const float* W  = (t==0) ? whh   : Wc;
    const float* bs = (t==0) ? bias0 : bias1;
    const float* hp = (t==0) ? h0    : outs + (t-1)*H_;
    int hps         = (t==0) ? H_    : T_*H_;
    hipLaunchKernelGGL(k_lstm, dim3(4,32), dim3(256), 0, stream,
                       hp, hps, cbuf, W, bs, outs + t*H_, T_*H_);
  }

  // fcout as MFMA GEMM: M=640 N=512 K=256, grid(10,4)
  hipLaunchKernelGGL((k_fcmm<256>), dim3(10,4), dim3(256), 0, stream, outs, Fof, fob, feats, 512);
  // cnnfc as MFMA GEMM: M=640 N=4096 K=512, grid(10,32)
  hipLaunchKernelGGL((k_fcmm<512>), dim3(10,32), dim3(256), 0, stream, feats, Whf, cfb, fc1, 4096);

  hipLaunchKernelGGL((k_wz<256,128>), dim3(4608), dim3(256), 0, stream, dw0, Wz0);
  hipLaunchKernelGGL((k_wz<128,64>),  dim3(1152), dim3(256), 0, stream, dw1, Wz1);
  hipLaunchKernelGGL((k_wz<64,32>),   dim3(288),  dim3(256), 0, stream, dw2, Wz2);

  // L0 (MFMA): IC=256 OC=128 IH=4, NL=4 RB=4 SR=4 BM=64, grid(160,4), CB=320
  hipLaunchKernelGGL((k_gemmdc<256,128,4,4,4,4,64,false>), dim3(160,4), dim3(256), 0, stream,
                     fc1, Wz0, conv0, (const float*)nullptr, (const float*)nullptr, scr0, 320);
  hipLaunchKernelGGL(k_bnred, dim3(128), dim3(256), 0, stream, scr0, sum0, sq0, 320);
  hipLaunchKernelGGL((k_bn<128,64>),   dim3(5120),  dim3(256), 0, stream, conv0, sum0, sq0, g0, be0, 1310720);

  // L1 (MFMA): IC=128 OC=64 IH=8, NL=2 RB=8 SR=8 BM=128, grid(320,2), CB=640
  hipLaunchKernelGGL((k_gemmdc<128,64,8,2,8,8,128,false>), dim3(320,2), dim3(256), 0, stream,
                     conv0, Wz1, conv1, (const float*)nullptr, (const float*)nullptr, scr1, 640);
  hipLaunchKernelGGL(k_bnred, dim3(64), dim3(256), 0, stream, scr1, sum1, sq1, 640);
  hipLaunchKernelGGL((k_bn<64,256>),   dim3(10240), dim3(256), 0, stream, conv1, sum1, sq1, g1, be1, 2621440);

  // L2 (MFMA): IC=64 OC=32 IH=16, NL=1 RB=8 SR=10 BM=128, grid(1280,1), CB=2560
  hipLaunchKernelGGL((k_gemmdc<64,32,16,1,8,10,128,false>), dim3(1280,1), dim3(256), 0, stream,
                     conv1, Wz2, conv2, (const float*)nullptr, (const float*)nullptr, scr2, 2560);
  hipLaunchKernelGGL(k_bnred, dim3(32), dim3(256), 0, stream, scr2, sum2, sq2, 2560);
  hipLaunchKernelGGL((k_bn<32,1024>),  dim3(20480), dim3(256), 0, stream, conv2, sum2, sq2, g2, be2, 5242880);

  // final
  hipLaunchKernelGGL(k_final, dim3(4,640), dim3(256), 0, stream, conv2, fw, (float*)d_out, fb);
}

// Round 13
// 424.876 us; speedup vs baseline: 2.1363x; 1.1633x over previous
//
#include <hip/hip_runtime.h>
#include <math.h>

#define B_ 32
#define T_ 20
#define H_ 256
#define F_ 512
#define NT_ 640

typedef __attribute__((ext_vector_type(8))) _Float16 half8v;
typedef __attribute__((ext_vector_type(4))) float f32x4;

__device__ __forceinline__ float sigf(float x){ return 1.f/(1.f+__expf(-x)); }
__device__ __forceinline__ float lrelu(float x){ return x>0.f ? x : 0.2f*x; }
__device__ __forceinline__ float dot4(float4 a, float4 b){
  return fmaf(a.x,b.x, fmaf(a.y,b.y, fmaf(a.z,b.z, a.w*b.w)));
}
__device__ __forceinline__ unsigned short f16bits(float x){
  _Float16 h = (_Float16)x;                 // RNE
  union { _Float16 h; unsigned short u; } cv; cv.h = h; return cv.u;
}

// Wc = w_ih + w_hh
__global__ void k_wc(const float* __restrict__ wih, const float* __restrict__ whh,
                     float* __restrict__ Wc){
  int i = blockIdx.x*256 + threadIdx.x;
  float4 a = ((const float4*)wih)[i];
  float4 b = ((const float4*)whh)[i];
  ((float4*)Wc)[i] = make_float4(a.x+b.x, a.y+b.y, a.z+b.z, a.w+b.w);
}

// bias1 = b_ih + b_hh ; bias0 = init_inp @ w_ih.T + bias1
__global__ void k_bias(const float* __restrict__ wih, const float* __restrict__ bih,
                       const float* __restrict__ bhh, const float* __restrict__ init_inp,
                       float* __restrict__ bias0, float* __restrict__ bias1){
  __shared__ __align__(16) float xs[H_];
  int tid = threadIdx.x;
  xs[tid] = init_inp[tid];
  __syncthreads();
  int j = blockIdx.x*256 + tid;
  const float4* wr = (const float4*)(wih + (size_t)j*H_);
  const float4* xx = (const float4*)xs;
  float acc = 0.f;
  #pragma unroll 8
  for(int k=0;k<H_/4;k++) acc += dot4(wr[k], xx[k]);
  float b1 = bih[j] + bhh[j];
  bias1[j] = b1;
  bias0[j] = acc + b1;
}

// out[b][j] = z[b] . W[j] + bias[j]
__global__ void k_rowfc(const float* __restrict__ z, const float* __restrict__ W,
                        const float* __restrict__ bias, float* __restrict__ out){
  __shared__ __align__(16) float zs[H_];
  int b = blockIdx.x, j = threadIdx.x;
  zs[j] = z[b*H_ + j];
  __syncthreads();
  const float4* wr = (const float4*)(W + (size_t)j*H_);
  const float4* zz = (const float4*)zs;
  float acc = bias[j];
  #pragma unroll 8
  for(int k=0;k<H_/4;k++) acc += dot4(wr[k], zz[k]);
  out[b*H_+j] = acc;
}

// one LSTM step, fp16 weights (fp32 math). n-order output. grid (4,32), block 256.
__global__ void k_lstm(const float* __restrict__ hprev, int hp_stride,
                       float* __restrict__ c,
                       const unsigned short* __restrict__ Wf, const float* __restrict__ bias,
                       float* __restrict__ hout, int ho_stride){
  __shared__ __align__(16) float hs[H_];
  __shared__ float gs[4][64];
  int b = blockIdx.y, jg = blockIdx.x, tid = threadIdx.x;
  hs[tid] = hprev[(size_t)b*hp_stride + tid];
  __syncthreads();
  int g = tid>>6, jj = tid&63;
  int row = g*H_ + jg*64 + jj;
  const half8v* wr = (const half8v*)(Wf + (size_t)row*H_);
  float acc = bias[row];
  #pragma unroll 8
  for(int k=0;k<H_/8;k++){
    half8v w8 = wr[k];
    const float* hp8 = hs + k*8;
    #pragma unroll
    for(int e=0;e<8;e++) acc = fmaf((float)w8[e], hp8[e], acc);
  }
  gs[g][jj] = acc;
  __syncthreads();
  if(tid < 64){
    int j = jg*64 + tid;
    float iv = gs[0][tid], fv = gs[1][tid], gv = gs[2][tid], ov = gs[3][tid];
    int ci = b*H_ + j;
    float cn = sigf(fv)*c[ci] + sigf(iv)*tanhf(gv);
    c[ci] = cn;
    hout[(size_t)b*ho_stride + j] = sigf(ov)*tanhf(cn);
  }
}

// fp32 -> fp16 elementwise (8 per thread)
__global__ void k_wcvt(const float* __restrict__ w, unsigned short* __restrict__ o, int n8){
  int i = blockIdx.x*256 + threadIdx.x;
  if(i >= n8) return;
  int base = i*8;
  float4 v0 = *(const float4*)(w+base);
  float4 v1 = *(const float4*)(w+base+4);
  unsigned short h[8] = {f16bits(v0.x),f16bits(v0.y),f16bits(v0.z),f16bits(v0.w),
                         f16bits(v1.x),f16bits(v1.y),f16bits(v1.z),f16bits(v1.w)};
  *(uint4*)(o+base) = *(uint4*)h;
}

// ---------------------------------------------------------------------------
// MFMA FC: C[m][n] = leaky(A[m][:K] . Wh[n][:K] + bias[n]).  BM=64 BN=128 BK=32.
template<int Kt>
__global__ __launch_bounds__(256) void k_fcmm(const float* __restrict__ A,
    const unsigned short* __restrict__ Wh, const float* __restrict__ bias,
    float* __restrict__ C, int Nt){
  constexpr int NK = Kt/32;
  __shared__ unsigned short at[64*40];
  __shared__ unsigned short bt[128*40];
  const int tid = threadIdx.x;
  const int m0 = blockIdx.x*64, n0 = blockIdx.y*128;
  const int arow = tid>>2, ach = tid&3;
  const float* pa = A + (size_t)(m0+arow)*Kt + ach*8;
  const int brow = tid>>1, bh = tid&1;
  const uint4* pb = (const uint4*)(Wh + (size_t)(n0+brow)*Kt + bh*16);
  float4 a0 = *(const float4*)pa;
  float4 a1 = *(const float4*)(pa+4);
  uint4 b0 = pb[0], b1 = pb[1];

  const int lane = tid&63, wvi = tid>>6;
  const int wm = wvi>>1, wn = wvi&1;
  const int l15 = lane&15, lh = lane>>4;

  f32x4 acc[2][4] = {};
  for(int ks=0; ks<NK; ++ks){
    __syncthreads();
    {
      unsigned short h[8] = {f16bits(a0.x),f16bits(a0.y),f16bits(a0.z),f16bits(a0.w),
                             f16bits(a1.x),f16bits(a1.y),f16bits(a1.z),f16bits(a1.w)};
      *(uint4*)&at[arow*40 + ach*8] = *(uint4*)h;
    }
    *(uint4*)&bt[brow*40 + bh*16    ] = b0;
    *(uint4*)&bt[brow*40 + bh*16 + 8] = b1;
    __syncthreads();
    if(ks+1 < NK){
      a0 = *(const float4*)(pa + (ks+1)*32);
      a1 = *(const float4*)(pa + (ks+1)*32 + 4);
      b0 = pb[(ks+1)*4]; b1 = pb[(ks+1)*4 + 1];
    }
    half8v Af[2], Bf[4];
    #pragma unroll
    for(int a=0;a<2;a++)
      Af[a] = *(const half8v*)&at[(wm*32 + a*16 + l15)*40 + lh*8];
    #pragma unroll
    for(int b=0;b<4;b++)
      Bf[b] = *(const half8v*)&bt[(wn*64 + b*16 + l15)*40 + lh*8];
    #pragma unroll
    for(int a=0;a<2;a++)
      #pragma unroll
      for(int b=0;b<4;b++)
        acc[a][b] = __builtin_amdgcn_mfma_f32_16x16x32_f16(Af[a], Bf[b], acc[a][b], 0, 0, 0);
  }
  #pragma unroll
  for(int b=0;b<4;b++){
    int n = n0 + wn*64 + b*16 + l15;
    float bv = bias[n];
    #pragma unroll
    for(int a=0;a<2;a++){
      #pragma unroll
      for(int r=0;r<4;r++){
        int m = m0 + wm*32 + a*16 + lh*4 + r;
        C[(size_t)m*Nt + n] = lrelu(acc[a][b][r] + bv);
      }
    }
  }
}

// ---------------------------------------------------------------------------
// weight transform: Wz[n=(oc*4+py*2+px)][k=(dy3*3+dx3)*IC+ic] (fp16, k-fastest)
template<int IC, int OC>
__global__ void k_wz(const float* __restrict__ w, unsigned short* __restrict__ Wz){
  constexpr int K9 = 9*IC, N4 = 4*OC;
  int i = blockIdx.x*256 + threadIdx.x;
  if(i >= N4*K9) return;
  int n = i / K9; int k = i - n*K9;
  int oc = n>>2, py = (n>>1)&1, px = n&1;
  int dd = k / IC; int ic = k - dd*IC;
  int dy3 = dd/3, dx3 = dd - 3*dy3;
  int ky = py + 3 - 2*dy3, kx = px + 3 - 2*dx3;
  float v = 0.f;
  if(ky>=0 && ky<4 && kx>=0 && kx<4)
    v = w[(((size_t)ic*OC + oc)*4 + ky)*4 + kx];
  Wz[i] = f16bits(v);
}

// ---------------------------------------------------------------------------
// MFMA implicit-GEMM deconv, fp16 operands, fp32 accum. OPERAND-SWAPPED
// (l15->M coalesced stores, (lh,r)->N). BN+leaky of the PREVIOUS layer fused
// into staging when BNIN — applied ONLY to in-bounds rows (halo stays zero!).
// Stats: per-(oc,block,wm) float2 partials to scratch (no global atomics).
template<int IC, int OC, int IH, int NL, int RB, int SR, int BM, bool BNIN>
__global__ __launch_bounds__(256) void k_gemmdc(
    const float* __restrict__ in, const unsigned short* __restrict__ Wz,
    float* __restrict__ out, const float* __restrict__ sc, const float* __restrict__ sh,
    float2* __restrict__ scr, int CB)
{
  constexpr int IW = IH, OW = 2*IH;
  constexpr int S  = IH*IW, S4 = 4*S;
  constexpr int K9 = 9*IC;
  constexpr int ICp = IC + 8;
  constexpr int TS = IH/RB;
  constexpr int P  = NL*SR*IW;
  constexpr int NK = K9/32;
  constexpr int BN = 128;
  constexpr int AM = BM/32;
  static_assert(NL*RB*IW == BM, "BM mismatch");

  __shared__ unsigned short linH[P*ICp];
  __shared__ unsigned short bt[BN*32];

  const int tid = threadIdx.x;
  const int bm = blockIdx.x, bn0 = blockIdx.y*BN;
  const int nimg0 = (bm/TS)*NL;
  const int rg = bm % TS;
  const int W0 = (SR==IH) ? 0 : (rg*RB - 1);

  const int pf_n = tid>>1, pf_h = tid&1;
  const uint4* pf_base = (const uint4*)(Wz + (size_t)(bn0+pf_n)*K9 + pf_h*16);
  uint4 breg0, breg1;

  // ---- stage A slab (fp16 channel-last), fused BN+leaky ONLY on valid rows
  {
    constexpr int NIT = P*(IC/8)/256;
    #pragma unroll
    for(int it=0; it<NIT; ++it){
      int i = tid + it*256;
      int p = i % P; int icb = (i/P)*8;
      int x = p % IW; int t1 = p/IW; int j = t1 % SR; int nl = t1/SR;
      int gr = W0 + j;
      bool ok = (gr>=0) && (gr<IH);
      const float* src = in + ((size_t)(nimg0+nl)*IC + icb)*S + gr*IW + x;
      unsigned short hh[8];
      #pragma unroll
      for(int e=0;e<8;e++){
        float v = 0.f;
        if(ok){
          v = src[(size_t)e*S];
          if(BNIN) v = lrelu(fmaf(v, sc[icb+e], sh[icb+e]));
        }
        hh[e] = f16bits(v);
      }
      *(uint4*)&linH[p*ICp + icb] = *(uint4*)hh;
    }
  }
  breg0 = pf_base[0]; breg1 = pf_base[1];

  const int lane = tid & 63, wvi = tid>>6;
  const int wm = wvi>>1, wn = wvi&1;
  const int l15 = lane & 15, lh = lane>>4;

  int mxA[AM], mylA[AM], nlA[AM];
  #pragma unroll
  for(int a=0;a<AM;a++){
    int r = wm*(BM/2) + a*16 + l15;
    mxA[a] = r % IW; int t = r/IW; mylA[a] = t % RB; nlA[a] = t/RB;
  }

  f32x4 acc[AM][4] = {};

  for(int ks=0; ks<NK; ++ks){
    __syncthreads();
    *(uint4*)&bt[pf_n*32 + pf_h*16    ] = breg0;
    *(uint4*)&bt[pf_n*32 + pf_h*16 + 8] = breg1;
    __syncthreads();
    if(ks+1 < NK){
      breg0 = pf_base[(ks+1)*4];
      breg1 = pf_base[(ks+1)*4 + 1];
    }

    int k0 = ks*32;
    int dd = k0 / IC; int icb = k0 - dd*IC;
    int dy3 = dd/3, dx3 = dd - 3*dy3;

    half8v Af[AM], Bf[4];
    #pragma unroll
    for(int a=0;a<AM;a++){
      int gx = mxA[a] - 1 + dx3;
      bool vx = (gx>=0) && (gx<IW);
      int gxc = gx<0 ? 0 : (gx>IW-1 ? IW-1 : gx);
      int jyc; bool vy;
      if(SR==IH){
        int jy = mylA[a] - 1 + dy3;
        vy = (jy>=0) && (jy<IH);
        jyc = jy<0 ? 0 : (jy>SR-1 ? SR-1 : jy);
      } else {
        jyc = mylA[a] + dy3; vy = true;   // halo rows staged (zero-filled OOB)
      }
      int p = (nlA[a]*SR + jyc)*IW + gxc;
      half8v f = *(const half8v*)&linH[p*ICp + icb + lh*8];
      if(!(vx&&vy)){
        #pragma unroll
        for(int e=0;e<8;e++) f[e] = (_Float16)0.f;
      }
      Af[a] = f;
    }
    #pragma unroll
    for(int b=0;b<4;b++)
      Bf[b] = *(const half8v*)&bt[(wn*64 + b*16 + l15)*32 + lh*8];

    #pragma unroll
    for(int a=0;a<AM;a++)
      #pragma unroll
      for(int b=0;b<4;b++)
        acc[a][b] = __builtin_amdgcn_mfma_f32_16x16x32_f16(Bf[b], Af[a], acc[a][b], 0, 0, 0);
  }

  // ---- epilogue: coalesced stores (l15 -> mx) + scratch stats
  #pragma unroll
  for(int b=0;b<4;b++){
    float s_ = 0.f, q_ = 0.f;
    int Nbase = bn0 + wn*64 + b*16 + lh*4;
    #pragma unroll
    for(int r=0;r<4;r++){
      int N = Nbase + r;
      int oc = N>>2, py = (N>>1)&1, px = N&1;
      #pragma unroll
      for(int a=0;a<AM;a++){
        float v = acc[a][b][r];
        int myg = (SR==IH) ? mylA[a] : (rg*RB + mylA[a]);
        out[((size_t)(nimg0+nlA[a])*OC + oc)*S4 + (size_t)(2*myg+py)*OW + (2*mxA[a]+px)] = v;
        s_ += v; q_ = fmaf(v,v,q_);
      }
    }
    s_ += __shfl_xor(s_,1); q_ += __shfl_xor(q_,1);
    s_ += __shfl_xor(s_,2); q_ += __shfl_xor(q_,2);
    s_ += __shfl_xor(s_,4); q_ += __shfl_xor(q_,4);
    s_ += __shfl_xor(s_,8); q_ += __shfl_xor(q_,8);
    if(l15 == 0){
      int oc = ((bn0 + wn*64 + b*16)>>2) + lh;
      scr[(size_t)oc*CB + bm*2 + wm] = make_float2(s_, q_);
    }
  }
}

// reduce per-block float2 partials -> sum/sq per oc. grid(OC), block 256.
__global__ void k_bnred(const float2* __restrict__ scr, float* __restrict__ sum,
                        float* __restrict__ sq, int CB){
  int oc = blockIdx.x, tid = threadIdx.x;
  float s = 0.f, q = 0.f;
  for(int i = tid; i < CB; i += 256){
    float2 v = scr[(size_t)oc*CB + i];
    s += v.x; q += v.y;
  }
  #pragma unroll
  for(int m=1;m<64;m<<=1){ s += __shfl_xor(s,m); q += __shfl_xor(q,m); }
  __shared__ float ls[4], lq[4];
  int w = tid>>6;
  if((tid&63)==0){ ls[w]=s; lq[w]=q; }
  __syncthreads();
  if(tid==0){
    sum[oc] = ls[0]+ls[1]+ls[2]+ls[3];
    sq[oc]  = lq[0]+lq[1]+lq[2]+lq[3];
  }
}

// sc/sh from accumulated stats (same math as the old k_bn).
__global__ void k_bnscale(const float* __restrict__ ssum, const float* __restrict__ ssq,
                          const float* __restrict__ g, const float* __restrict__ be,
                          float* __restrict__ sc, float* __restrict__ sh,
                          int OCn, float inv_cnt){
  int t = threadIdx.x;
  if(t < OCn){
    float m = ssum[t]*inv_cnt;
    float var = ssq[t]*inv_cnt - m*m;
    float s = g[t]*rsqrtf(var + 1e-5f);
    sc[t] = s; sh[t] = be[t] - m*s;
  }
}

// ---------------------------------------------------------------------------
// final ConvTranspose (32->1) + sigmoid; BN2+leaky fused into staging
// (clamped rows are real data; compute-time mask zeroes border taps).
__global__ __launch_bounds__(256,3) void k_final(const float* __restrict__ in,
    const float* __restrict__ w, float* __restrict__ dout, const float* __restrict__ fb,
    const float* __restrict__ sc, const float* __restrict__ sh){
  constexpr int IC = 32, IH = 32, IW = 32, OW = 64, RB = 8, SR = RB+2;
  __shared__ float lin[IC*SR*IW];
  __shared__ __align__(16) float lw[IC*16];

  int rg = blockIdx.x;
  int n = blockIdx.y;
  int tid = threadIdx.x;

  {
    const float4* src = (const float4*)in;
    float4* dst = (float4*)lin;
    constexpr int NV4 = IC*SR*IW/4;
    #pragma unroll
    for(int i=0;i<NV4/256;i++){
      int idx = tid + i*256;
      int ic = idx/(SR*8); int rem = idx - ic*(SR*8);
      int j = rem/8; int c4 = rem - j*8;
      int gr = RB*rg - 1 + j;
      gr = gr < 0 ? 0 : (gr > IH-1 ? IH-1 : gr);
      float4 v = src[((size_t)(n*IC+ic)*IH + gr)*8 + c4];
      float s = sc[ic], h2 = sh[ic];
      v.x = lrelu(fmaf(v.x, s, h2));
      v.y = lrelu(fmaf(v.y, s, h2));
      v.z = lrelu(fmaf(v.z, s, h2));
      v.w = lrelu(fmaf(v.w, s, h2));
      dst[idx] = v;
    }
    if(tid < 128) ((float4*)lw)[tid] = ((const float4*)w)[tid];
  }
  float fbv = fb[0];
  __syncthreads();

  int tl = tid / IW, tx = tid % IW;
  int ty = RB*rg + tl;

  int offs[3][3]; float msk[3][3];
  #pragma unroll
  for(int dy=0;dy<3;dy++){
    int iy = ty-1+dy; bool vy = (iy>=0)&&(iy<IH);
    #pragma unroll
    for(int dx=0;dx<3;dx++){
      int ix = tx-1+dx; bool vx = (ix>=0)&&(ix<IW);
      int lcol = ix < 0 ? 0 : (ix > IW-1 ? IW-1 : ix);
      offs[dy][dx] = (tl+dy)*IW + lcol;
      msk[dy][dx]  = (vy&&vx) ? 1.f : 0.f;
    }
  }

  float acc[2][2] = {{0.f,0.f},{0.f,0.f}};
  #pragma unroll 4
  for(int ic=0; ic<IC; ic++){
    const float* p = lin + ic*(SR*IW);
    float v[3][3];
    #pragma unroll
    for(int dy=0;dy<3;dy++)
      #pragma unroll
      for(int dx=0;dx<3;dx++)
        v[dy][dx] = p[offs[dy][dx]] * msk[dy][dx];
    const float4* wr = (const float4*)(lw + ic*16);
    float4 w0=wr[0], w1=wr[1], w2=wr[2], w3=wr[3];
    float wv[16] = {w0.x,w0.y,w0.z,w0.w, w1.x,w1.y,w1.z,w1.w,
                    w2.x,w2.y,w2.z,w2.w, w3.x,w3.y,w3.z,w3.w};
    #pragma unroll
    for(int r=0;r<2;r++)
      #pragma unroll
      for(int s2=0;s2<2;s2++)
        #pragma unroll
        for(int a=0;a<2;a++)
          #pragma unroll
          for(int b2=0;b2<2;b2++)
            acc[r][s2] = fmaf(v[a+r][b2+s2], wv[(3-2*a-r)*4 + (3-2*b2-s2)], acc[r][s2]);
  }

  float* ob = dout + (size_t)n*OW*OW;
  #pragma unroll
  for(int r=0;r<2;r++)
    #pragma unroll
    for(int s2=0;s2<2;s2++){
      float vv = acc[r][s2] + fbv;
      ob[(2*ty+r)*OW + (2*tx+s2)] = 1.f/(1.f+__expf(-vv));
    }
}

extern "C" void kernel_launch(void* const* d_in, const int* in_sizes, int n_in,
                              void* d_out, int out_size, void* d_ws, size_t ws_size,
                              hipStream_t stream){
  const float* z       = (const float*)d_in[0];
  const float* fhw     = (const float*)d_in[1];
  const float* fhb     = (const float*)d_in[2];
  const float* fcw     = (const float*)d_in[3];
  const float* fcb     = (const float*)d_in[4];
  const float* wih     = (const float*)d_in[5];
  const float* bih     = (const float*)d_in[6];
  const float* whh     = (const float*)d_in[7];
  const float* bhh     = (const float*)d_in[8];
  const float* init_inp= (const float*)d_in[9];
  const float* fow     = (const float*)d_in[10];
  const float* fob     = (const float*)d_in[11];
  const float* cfw     = (const float*)d_in[12];
  const float* cfb     = (const float*)d_in[13];
  const float* dw0     = (const float*)d_in[14];
  const float* g0      = (const float*)d_in[15];
  const float* be0     = (const float*)d_in[16];
  const float* dw1     = (const float*)d_in[17];
  const float* g1      = (const float*)d_in[18];
  const float* be1     = (const float*)d_in[19];
  const float* dw2     = (const float*)d_in[20];
  const float* g2      = (const float*)d_in[21];
  const float* be2     = (const float*)d_in[22];
  const float* fw      = (const float*)d_in[23];
  const float* fb      = (const float*)d_in[24];

  float* ws    = (float*)d_ws;
  float* conv2 = ws;                 // 640*32*1024 = 20971520 floats
  float* conv1 = ws + 20971520;      // 640*64*256  = 10485760
  float* conv0 = ws + 31457280;      // 640*128*64  =  5242880
  float* fc1   = ws + 36700160;      // 640*4096    =  2621440
  float* feats = ws + 39321600;      // 640*512     =   327680
  float* outs  = ws + 39649280;      // 640*256     =   163840 (n-order h)
  float* Wc    = ws + 39813120;      // 1024*256    =   262144
  float* bias0 = ws + 40075264;      // 1024
  float* bias1 = ws + 40076288;      // 1024
  float* h0    = ws + 40077312;      // 8192
  float* cbuf  = ws + 40085504;      // 8192
  float* stats = ws + 40093696;      // 448
  float* scsh  = ws + 40094144;      // 448 (sc/sh for the 3 BN layers)
  float* sum0 = stats,     *sq0 = stats+128;
  float* sum1 = stats+256, *sq1 = stats+320;
  float* sum2 = stats+384, *sq2 = stats+416;
  float* sc0 = scsh,      *sh0 = scsh+128;
  float* sc1 = scsh+256,  *sh1 = scsh+320;
  float* sc2 = scsh+384,  *sh2 = scsh+416;

  // transformed weights + stats scratch live in regions dead at use time
  // (all inside conv2, consumed before the L2 gemm writes conv2):
  unsigned short* Wz0   = (unsigned short*)conv2;                 // 589824 sh
  unsigned short* Wz1   = (unsigned short*)(conv2 + 600000);      // 147456 sh
  unsigned short* Whf   = (unsigned short*)(conv2 + 1000000);     // 4096*512
  unsigned short* Fof   = (unsigned short*)(conv2 + 2100000);     // 512*256
  unsigned short* Wc16  = (unsigned short*)(conv2 + 2200000);     // 1024*256
  unsigned short* Whh16 = (unsigned short*)(conv2 + 2400000);     // 1024*256
  unsigned short* Wz2   = (unsigned short*)feats;                 // 128*576
  float2* scr0 = (float2*)outs;                 // 128 oc * 320
  float2* scr1 = (float2*)(outs + 81920);       // 64 oc * 640
  float2* scr2 = (float2*)(feats + 40960);      // 32 oc * 2560

  hipLaunchKernelGGL(k_wc,    dim3(256), dim3(256), 0, stream, wih, whh, Wc);
  hipLaunchKernelGGL(k_bias,  dim3(4),   dim3(256), 0, stream, wih, bih, bhh, init_inp, bias0, bias1);
  hipLaunchKernelGGL(k_rowfc, dim3(32),  dim3(256), 0, stream, z, fhw, fhb, h0);
  hipLaunchKernelGGL(k_rowfc, dim3(32),  dim3(256), 0, stream, z, fcw, fcb, cbuf);
  hipLaunchKernelGGL(k_wcvt,  dim3(1024), dim3(256), 0, stream, cfw, Whf, 262144);
  hipLaunchKernelGGL(k_wcvt,  dim3(64),   dim3(256), 0, stream, fow, Fof, 16384);
  hipLaunchKernelGGL(k_wcvt,  dim3(128),  dim3(256), 0, stream, whh, Whh16, 32768);
  hipLaunchKernelGGL(k_wcvt,  dim3(128),  dim3(256), 0, stream, Wc, Wc16, 32768);

  // LSTM: 20 per-step launches, fp16 weights, n-order output
  for(int t=0;t<T_;t++){
    const unsigned short* Wf = (t==0) ? Whh16 : Wc16;
    const float* bs = (t==0) ? bias0 : bias1;
    const float* hp = (t==0) ? h0    : outs + (t-1)*H_;
    int hps         = (t==0) ? H_    : T_*H_;
    hipLaunchKernelGGL(k_lstm, dim3(4,32), dim3(256), 0, stream,
                       hp, hps, cbuf, Wf, bs, outs + t*H_, T_*H_);
  }

  // fcout as MFMA GEMM: M=640 N=512 K=256, grid(10,4)
  hipLaunchKernelGGL((k_fcmm<256>), dim3(10,4), dim3(256), 0, stream, outs, Fof, fob, feats, 512);
  // cnnfc as MFMA GEMM: M=640 N=4096 K=512, grid(10,32)
  hipLaunchKernelGGL((k_fcmm<512>), dim3(10,32), dim3(256), 0, stream, feats, Whf, cfb, fc1, 4096);

  hipLaunchKernelGGL((k_wz<256,128>), dim3(4608), dim3(256), 0, stream, dw0, Wz0);
  hipLaunchKernelGGL((k_wz<128,64>),  dim3(1152), dim3(256), 0, stream, dw1, Wz1);
  hipLaunchKernelGGL((k_wz<64,32>),   dim3(288),  dim3(256), 0, stream, dw2, Wz2);

  // L0 (MFMA): grid(160,4), CB=320 — raw output + stats
  hipLaunchKernelGGL((k_gemmdc<256,128,4,4,4,4,64,false>), dim3(160,4), dim3(256), 0, stream,
                     fc1, Wz0, conv0, (const float*)nullptr, (const float*)nullptr, scr0, 320);
  hipLaunchKernelGGL(k_bnred,  dim3(128), dim3(256), 0, stream, scr0, sum0, sq0, 320);
  hipLaunchKernelGGL(k_bnscale, dim3(1), dim3(128), 0, stream, sum0, sq0, g0, be0, sc0, sh0,
                     128, 1.f/(640.f*64.f));

  // L1 (MFMA, BN0 fused into staging): grid(320,2), CB=640
  hipLaunchKernelGGL((k_gemmdc<128,64,8,2,8,8,128,true>), dim3(320,2), dim3(256), 0, stream,
                     conv0, Wz1, conv1, sc0, sh0, scr1, 640);
  hipLaunchKernelGGL(k_bnred,  dim3(64), dim3(256), 0, stream, scr1, sum1, sq1, 640);
  hipLaunchKernelGGL(k_bnscale, dim3(1), dim3(128), 0, stream, sum1, sq1, g1, be1, sc1, sh1,
                     64, 1.f/(640.f*256.f));

  // L2 (MFMA, BN1 fused into staging, halo rows stay ZERO): grid(1280,1), CB=2560
  hipLaunchKernelGGL((k_gemmdc<64,32,16,1,8,10,128,true>), dim3(1280,1), dim3(256), 0, stream,
                     conv1, Wz2, conv2, sc1, sh1, scr2, 2560);
  hipLaunchKernelGGL(k_bnred,  dim3(32), dim3(256), 0, stream, scr2, sum2, sq2, 2560);
  hipLaunchKernelGGL(k_bnscale, dim3(1), dim3(128), 0, stream, sum2, sq2, g2, be2, sc2, sh2,
                     32, 1.f/(640.f*1024.f));

  // final: BN2+leaky fused into staging
  hipLaunchKernelGGL(k_final, dim3(4,640), dim3(256), 0, stream, conv2, fw, (float*)d_out, fb, sc2, sh2);
}